// Round 1
// baseline (336.058 us; speedup 1.0000x reference)
//
#include <hip/hip_runtime.h>
#include <stdint.h>

typedef __attribute__((ext_vector_type(8))) short bf16x8;
typedef __attribute__((ext_vector_type(4))) float f32x4;

__device__ __forceinline__ unsigned short f2bf(float f) {
  unsigned int u = __float_as_uint(f);
  u += 0x7FFFu + ((u >> 16) & 1u);
  return (unsigned short)(u >> 16);
}

#define MFMA16(a, b, c) __builtin_amdgcn_mfma_f32_16x16x32_bf16((a), (b), (c), 0, 0, 0)

__device__ __forceinline__ void gload_lds16(const void* g, void* l) {
  __builtin_amdgcn_global_load_lds((const __attribute__((address_space(1))) void*)g,
                                   (__attribute__((address_space(3))) void*)l, 16, 0, 0);
}

// ---------------- cast fp32 -> bf16 ----------------
__global__ void cast_kernel(const float* __restrict__ src, unsigned short* __restrict__ dst, int n) {
  int i = (blockIdx.x * 256 + threadIdx.x) * 4;
  if (i >= n) return;
  const float4 v = *reinterpret_cast<const float4*>(src + i);
  ushort4 o;
  o.x = f2bf(v.x); o.y = f2bf(v.y); o.z = f2bf(v.z); o.w = f2bf(v.w);
  *reinterpret_cast<ushort4*>(dst + i) = o;
}

// ---------------- GEMM: out[m][n] = sum_k A[m][k]*B[n][k] + bias[n] ----------------
// MODE 0: QKV projection, scatter-store Q/K (bf16 [bh][s][d]) and V transposed (bf16 [bh][d][s])
// MODE 1: output projection, store fp32 to outF
template <int MODE>
__global__ __launch_bounds__(256) void gemm_bt(
    const unsigned short* __restrict__ A, const unsigned short* __restrict__ B,
    const float* __restrict__ bias,
    unsigned short* __restrict__ Qb, unsigned short* __restrict__ Kb,
    unsigned short* __restrict__ Vtb, float* __restrict__ outF,
    int M, int N, int K) {
  __shared__ unsigned short As[128][32];
  __shared__ unsigned short Bs[128][32];
  const int tid  = threadIdx.x;
  const int w    = tid >> 6, lane = tid & 63;
  const int wr   = w >> 1, wc = w & 1;
  const int g    = lane >> 4, cc = lane & 15;
  const int bm   = blockIdx.y, bn = blockIdx.x;
  const long Arow0 = (long)bm * 128;
  const long Brow0 = (long)bn * 128;

  f32x4 acc[4][4];
#pragma unroll
  for (int i = 0; i < 4; i++)
#pragma unroll
    for (int j = 0; j < 4; j++) acc[i][j] = (f32x4){0.f, 0.f, 0.f, 0.f};

  const int sr = lane >> 2;       // 0..15 (row within 16-row chunk)
  const int sk = (lane & 3) * 8;  // k element offset 0/8/16/24

  for (int k0 = 0; k0 < K; k0 += 32) {
    __syncthreads();
#pragma unroll
    for (int j = 0; j < 2; j++) {
      const int r = w * 32 + j * 16 + sr;
      const unsigned short* ga = A + (Arow0 + r) * K + k0 + sk;
      const unsigned short* gb = B + (Brow0 + r) * K + k0 + sk;
      gload_lds16(ga, (char*)(&As[0][0]) + w * 2048 + j * 1024);
      gload_lds16(gb, (char*)(&Bs[0][0]) + w * 2048 + j * 1024);
    }
    __syncthreads();
    bf16x8 af[4], bf[4];
#pragma unroll
    for (int i = 0; i < 4; i++)
      af[i] = *reinterpret_cast<const bf16x8*>(&As[wr * 64 + i * 16 + cc][g * 8]);
#pragma unroll
    for (int j = 0; j < 4; j++)
      bf[j] = *reinterpret_cast<const bf16x8*>(&Bs[wc * 64 + j * 16 + cc][g * 8]);
#pragma unroll
    for (int i = 0; i < 4; i++)
#pragma unroll
      for (int j = 0; j < 4; j++) acc[i][j] = MFMA16(af[i], bf[j], acc[i][j]);
  }

#pragma unroll
  for (int i = 0; i < 4; i++) {
    const int grow0 = bm * 128 + wr * 64 + i * 16 + g * 4;
#pragma unroll
    for (int j = 0; j < 4; j++) {
      const int gcol = bn * 128 + wc * 64 + j * 16 + cc;
      const float bb = bias[gcol];
#pragma unroll
      for (int r = 0; r < 4; r++) {
        const float v  = acc[i][j][r] + bb;
        const int row  = grow0 + r;
        if (MODE == 0) {
          const int part = gcol >> 10;          // 0=Q 1=K 2=V
          const int ccl  = gcol & 1023;
          const int h    = ccl >> 6, d = ccl & 63;
          const int b    = row >> 11, s = row & 2047;
          const unsigned short u = f2bf(v);
          const size_t bh = (size_t)(b * 16 + h);
          if (part == 0)      Qb[(bh * 2048 + s) * 64 + d] = u;
          else if (part == 1) Kb[(bh * 2048 + s) * 64 + d] = u;
          else                Vtb[(bh * 64 + d) * 2048 + s] = u;
        } else {
          outF[(size_t)row * N + gcol] = v;
        }
      }
    }
  }
}

// ---------------- causal flash attention ----------------
// One wave per 16-row q-tile. K/Vt read directly from global (L2-resident).
__global__ __launch_bounds__(256) void attn_kernel(
    const unsigned short* __restrict__ Q, const unsigned short* __restrict__ K,
    const unsigned short* __restrict__ Vt, unsigned short* __restrict__ preO) {
  __shared__ unsigned short Plds[4][16][72];  // per-wave P tile, padded rows (144B) -> <=2-way conflicts
  const int w = threadIdx.x >> 6, lane = threadIdx.x & 63;
  const int g = lane >> 4, cc = lane & 15;
  const int wg = blockIdx.x * 4 + w;   // 0..4095
  const int bh = wg >> 7;              // 0..31
  const int qt = wg & 127;
  const int qbase = qt * 16;
  const unsigned short* Qp = Q  + (size_t)bh * 2048 * 64;
  const unsigned short* Kp = K  + (size_t)bh * 2048 * 64;
  const unsigned short* Vp = Vt + (size_t)bh * 64 * 2048;

  bf16x8 qf[2];
#pragma unroll
  for (int t = 0; t < 2; t++)
    qf[t] = *reinterpret_cast<const bf16x8*>(Qp + (size_t)(qbase + cc) * 64 + t * 32 + g * 8);

  f32x4 o[4];
#pragma unroll
  for (int n = 0; n < 4; n++) o[n] = (f32x4){0.f, 0.f, 0.f, 0.f};
  float mrun[4], lsum[4];
#pragma unroll
  for (int r = 0; r < 4; r++) { mrun[r] = -1e30f; lsum[r] = 0.f; }

  const int nkv = (qbase + 16 + 63) >> 6;
  for (int kb = 0; kb < nkv; kb++) {
    const int kbase = kb * 64;
    f32x4 s[4];
#pragma unroll
    for (int n = 0; n < 4; n++) s[n] = (f32x4){0.f, 0.f, 0.f, 0.f};
#pragma unroll
    for (int n = 0; n < 4; n++) {
#pragma unroll
      for (int t = 0; t < 2; t++) {
        bf16x8 kf = *reinterpret_cast<const bf16x8*>(
            Kp + (size_t)(kbase + n * 16 + cc) * 64 + t * 32 + g * 8);
        s[n] = MFMA16(qf[t], kf, s[n]);
      }
    }
    // scale + causal mask (matches reference: masked logits = -10000)
#pragma unroll
    for (int n = 0; n < 4; n++) {
      const int col = kbase + n * 16 + cc;
#pragma unroll
      for (int r = 0; r < 4; r++) {
        const int row = qbase + g * 4 + r;
        const float v = s[n][r] * 0.125f;
        s[n][r] = (col <= row) ? v : -10000.0f;
      }
    }
    // online softmax: row stats live in regs r for rows g*4+r, reduce over 16 lanes (cc)
    float bmax[4];
#pragma unroll
    for (int r = 0; r < 4; r++)
      bmax[r] = fmaxf(fmaxf(s[0][r], s[1][r]), fmaxf(s[2][r], s[3][r]));
#pragma unroll
    for (int msk = 1; msk < 16; msk <<= 1)
#pragma unroll
      for (int r = 0; r < 4; r++) bmax[r] = fmaxf(bmax[r], __shfl_xor(bmax[r], msk));
    float alpha[4];
#pragma unroll
    for (int r = 0; r < 4; r++) {
      const float mn = fmaxf(mrun[r], bmax[r]);
      alpha[r] = __expf(mrun[r] - mn);
      mrun[r] = mn;
    }
    float rs[4] = {0.f, 0.f, 0.f, 0.f};
#pragma unroll
    for (int n = 0; n < 4; n++)
#pragma unroll
      for (int r = 0; r < 4; r++) {
        const float p = __expf(s[n][r] - mrun[r]);
        s[n][r] = p;
        rs[r] += p;
      }
#pragma unroll
    for (int msk = 1; msk < 16; msk <<= 1)
#pragma unroll
      for (int r = 0; r < 4; r++) rs[r] += __shfl_xor(rs[r], msk);
#pragma unroll
    for (int r = 0; r < 4; r++) lsum[r] = lsum[r] * alpha[r] + rs[r];
#pragma unroll
    for (int n = 0; n < 4; n++)
#pragma unroll
      for (int r = 0; r < 4; r++) o[n][r] *= alpha[r];
    // P (D-layout) -> LDS -> A-layout fragments
#pragma unroll
    for (int n = 0; n < 4; n++)
#pragma unroll
      for (int r = 0; r < 4; r++) Plds[w][g * 4 + r][n * 16 + cc] = f2bf(s[n][r]);
    asm volatile("s_waitcnt lgkmcnt(0)" ::: "memory");
#pragma unroll
    for (int t = 0; t < 2; t++) {
      bf16x8 pf = *reinterpret_cast<const bf16x8*>(&Plds[w][cc][t * 32 + g * 8]);
#pragma unroll
      for (int n = 0; n < 4; n++) {
        bf16x8 vf = *reinterpret_cast<const bf16x8*>(
            Vp + (size_t)(n * 16 + cc) * 2048 + kbase + t * 32 + g * 8);
        o[n] = MFMA16(pf, vf, o[n]);
      }
    }
    asm volatile("s_waitcnt lgkmcnt(0)" ::: "memory");
  }

  const int b = bh >> 4, h = bh & 15;
#pragma unroll
  for (int r = 0; r < 4; r++) {
    const float inv = 1.0f / lsum[r];
    const size_t rowoff = ((size_t)b * 2048 + qbase + g * 4 + r) * 1024 + (size_t)h * 64;
#pragma unroll
    for (int n = 0; n < 4; n++) preO[rowoff + n * 16 + cc] = f2bf(o[n][r] * inv);
  }
}

extern "C" void kernel_launch(void* const* d_in, const int* in_sizes, int n_in,
                              void* d_out, int out_size, void* d_ws, size_t ws_size,
                              hipStream_t stream) {
  (void)in_sizes; (void)n_in; (void)out_size; (void)ws_size;
  const float* x    = (const float*)d_in[0];
  const float* Wqkv = (const float*)d_in[1];
  const float* bqkv = (const float*)d_in[2];
  const float* Wo   = (const float*)d_in[3];
  const float* bo   = (const float*)d_in[4];
  float* out = (float*)d_out;

  char* ws = (char*)d_ws;
  const size_t MB = 1024 * 1024;
  unsigned short* xb    = (unsigned short*)(ws);            //  8 MB
  unsigned short* wqkvb = (unsigned short*)(ws + 8 * MB);   //  6 MB
  unsigned short* wob   = (unsigned short*)(ws + 14 * MB);  //  2 MB
  unsigned short* Qb    = (unsigned short*)(ws + 16 * MB);  //  8 MB
  unsigned short* Kb    = (unsigned short*)(ws + 24 * MB);  //  8 MB
  unsigned short* Vtb   = (unsigned short*)(ws + 32 * MB);  //  8 MB
  unsigned short* preO  = (unsigned short*)(ws + 40 * MB);  //  8 MB (total 48 MB)

  cast_kernel<<<4096, 256, 0, stream>>>(x, xb, 4194304);
  cast_kernel<<<3072, 256, 0, stream>>>(Wqkv, wqkvb, 3145728);
  cast_kernel<<<1024, 256, 0, stream>>>(Wo, wob, 1048576);
  gemm_bt<0><<<dim3(24, 32), 256, 0, stream>>>(xb, wqkvb, bqkv, Qb, Kb, Vtb, nullptr,
                                               4096, 3072, 1024);
  attn_kernel<<<1024, 256, 0, stream>>>(Qb, Kb, Vtb, preO);
  gemm_bt<1><<<dim3(8, 32), 256, 0, stream>>>(preO, wob, bo, nullptr, nullptr, nullptr, out,
                                              4096, 1024, 1024);
}